// Round 1
// baseline (56.267 us; speedup 1.0000x reference)
//
#include <hip/hip_runtime.h>
#include <math.h>

#define NN 8192
#define NMODES 16
#define NB 32
#define NCH 64
#define NROWS (NB * NCH)       // 2048
#define TPB 256
#define JITER (NN / TPB)       // 32

// cos/sin(2*pi*m/32), m = 0..31 (compile-time constants; folded into SGPR
// operands of the fully-unrolled FMA loops)
constexpr float C32[32] = {
     1.0f,          0.980785280f,  0.923879533f,  0.831469612f,
     0.707106781f,  0.555570233f,  0.382683432f,  0.195090322f,
     0.0f,         -0.195090322f, -0.382683432f, -0.555570233f,
    -0.707106781f, -0.831469612f, -0.923879533f, -0.980785280f,
    -1.0f,         -0.980785280f, -0.923879533f, -0.831469612f,
    -0.707106781f, -0.555570233f, -0.382683432f, -0.195090322f,
     0.0f,          0.195090322f,  0.382683432f,  0.555570233f,
     0.707106781f,  0.831469612f,  0.923879533f,  0.980785280f
};
constexpr float S32[32] = {
     0.0f,          0.195090322f,  0.382683432f,  0.555570233f,
     0.707106781f,  0.831469612f,  0.923879533f,  0.980785280f,
     1.0f,          0.980785280f,  0.923879533f,  0.831469612f,
     0.707106781f,  0.555570233f,  0.382683432f,  0.195090322f,
     0.0f,         -0.195090322f, -0.382683432f, -0.555570233f,
    -0.707106781f, -0.831469612f, -0.923879533f, -0.980785280f,
    -1.0f,         -0.980785280f, -0.923879533f, -0.831469612f,
    -0.707106781f, -0.555570233f, -0.382683432f, -0.195090322f
};

// Stage 1: partial forward DFT. One block (256 thr) per (b, cin) row.
// Thread t accumulates over n = t + 256*j; coarse twiddle (2*pi*k*j/32) is a
// compile-time constant, fine twiddle e^{-i 2*pi*k*t/8192} applied once at end.
// Wave-reduces and stores per-wave partials (4 per row) for stage 2 to sum.
__global__ __launch_bounds__(TPB) void fwd_dft_kernel(
    const float* __restrict__ v, float* __restrict__ vfpart) {
  const int row = blockIdx.x;        // b*64 + i
  const int t = threadIdx.x;
  const float* __restrict__ vr = v + (size_t)row * NN;

  float ar[NMODES], ai[NMODES];
#pragma unroll
  for (int k = 0; k < NMODES; ++k) { ar[k] = 0.f; ai[k] = 0.f; }

#pragma unroll
  for (int j = 0; j < JITER; ++j) {
    float x = vr[t + TPB * j];
#pragma unroll
    for (int k = 0; k < NMODES; ++k) {
      const int m = (k * j) & 31;
      ar[k] = fmaf(x,  C32[m], ar[k]);
      ai[k] = fmaf(x, -S32[m], ai[k]);
    }
  }

  // base rotation e^{-i 2*pi*k*t/8192}: one double sincos + complex recurrence
  double phi = (double)t * (6.283185307179586476925287 / (double)NN);
  double spd, cpd;
  sincos(phi, &spd, &cpd);
  const float c1 = (float)cpd, s1 = (float)spd;

  float pr[NMODES], pi[NMODES];
  float ck = 1.f, sk = 0.f;
#pragma unroll
  for (int k = 0; k < NMODES; ++k) {
    pr[k] = ar[k] * ck + ai[k] * sk;
    pi[k] = ai[k] * ck - ar[k] * sk;
    const float cn = ck * c1 - sk * s1;
    const float sn = sk * c1 + ck * s1;
    ck = cn; sk = sn;
  }

  // butterfly reduce across the 64-lane wave
#pragma unroll
  for (int k = 0; k < NMODES; ++k) {
#pragma unroll
    for (int off = 32; off > 0; off >>= 1) {
      pr[k] += __shfl_xor(pr[k], off);
      pi[k] += __shfl_xor(pi[k], off);
    }
  }

  const int lane = t & 63, wave = t >> 6;
  if (lane == 0) {
    float* dst = vfpart + ((size_t)row * 4 + wave) * 32;
#pragma unroll
    for (int k = 0; k < NMODES; ++k) {
      dst[k]      = pr[k];
      dst[16 + k] = pi[k];
    }
  }
}

// Stage 2: complex channel mix lv[b,o,k] = sum_i W[k,o,i] * vf[b,i,k].
// Also sums the 4 per-wave partials from stage 1. Tiny kernel.
__global__ __launch_bounds__(256) void mix_kernel(
    const float* __restrict__ vfpart, const float* __restrict__ wre,
    const float* __restrict__ wim, float* __restrict__ lv) {
  const int k   = threadIdx.x & 15;
  const int olo = threadIdx.x >> 4;    // 0..15
  const int b   = blockIdx.x >> 2;     // 0..31
  const int o   = (blockIdx.x & 3) * 16 + olo;

  float lr = 0.f, li = 0.f;
  for (int i = 0; i < NCH; ++i) {
    const float* p = vfpart + ((size_t)(b * NCH + i) * 4) * 32;
    float vrr = 0.f, vii = 0.f;
#pragma unroll
    for (int w = 0; w < 4; ++w) {
      vrr += p[w * 32 + k];
      vii += p[w * 32 + 16 + k];
    }
    const float wr = wre[((size_t)k * NCH + o) * NCH + i];
    const float wi = wim[((size_t)k * NCH + o) * NCH + i];
    lr = fmaf(wr, vrr, fmaf(-wi, vii, lr));
    li = fmaf(wr, vii, fmaf( wi, vrr, li));
  }
  float* dst = lv + (size_t)(b * NCH + o) * 32;
  dst[k]      = lr;
  dst[16 + k] = li;
}

// Stage 3: inverse synthesis with only 16 modes.
// out[row, n] = sum_k P[k]*cos_c + Q[k]*sin_c where P,Q fold the per-thread
// base rotation, irfft scaling (1/N), and the factor-2 for k>=1.
// DC imaginary part is naturally ignored (S32[0] == 0), matching np.irfft.
__global__ __launch_bounds__(TPB) void inv_dft_kernel(
    const float* __restrict__ lv, float* __restrict__ out) {
  const int row = blockIdx.x;        // b*64 + o
  const int t = threadIdx.x;
  const float* __restrict__ L = lv + (size_t)row * 32;

  double phi = (double)t * (6.283185307179586476925287 / (double)NN);
  double spd, cpd;
  sincos(phi, &spd, &cpd);
  const float c1 = (float)cpd, s1 = (float)spd;

  float P[NMODES], Q[NMODES];
  float ck = 1.f, sk = 0.f;
#pragma unroll
  for (int k = 0; k < NMODES; ++k) {
    const float lr = L[k], li = L[16 + k];
    const float g = (k == 0) ? (1.0f / (float)NN) : (2.0f / (float)NN);
    P[k] =  g * (lr * ck - li * sk);
    Q[k] = -g * (lr * sk + li * ck);
    const float cn = ck * c1 - sk * s1;
    const float sn = sk * c1 + ck * s1;
    ck = cn; sk = sn;
  }

  float* __restrict__ orow = out + (size_t)row * NN;
#pragma unroll
  for (int j = 0; j < JITER; ++j) {
    float acc0 = 0.f, acc1 = 0.f;   // two chains for ILP
#pragma unroll
    for (int k = 0; k < NMODES; k += 2) {
      const int m0 = (k * j) & 31;
      const int m1 = ((k + 1) * j) & 31;
      acc0 = fmaf(P[k],     C32[m0], acc0);
      acc0 = fmaf(Q[k],     S32[m0], acc0);
      acc1 = fmaf(P[k + 1], C32[m1], acc1);
      acc1 = fmaf(Q[k + 1], S32[m1], acc1);
    }
    orow[t + TPB * j] = acc0 + acc1;
  }
}

extern "C" void kernel_launch(void* const* d_in, const int* in_sizes, int n_in,
                              void* d_out, int out_size, void* d_ws, size_t ws_size,
                              hipStream_t stream) {
  const float* v   = (const float*)d_in[0];   // [32, 64, 8192]
  const float* wre = (const float*)d_in[1];   // [16, 64, 64]
  const float* wim = (const float*)d_in[2];   // [16, 64, 64]
  float* out = (float*)d_out;                 // [32, 64, 8192]

  float* vfpart = (float*)d_ws;                        // 2048 * 4 * 32 floats = 1 MB
  float* lvbuf  = vfpart + (size_t)NROWS * 4 * 32;     // 2048 * 32 floats = 256 KB

  fwd_dft_kernel<<<NROWS, TPB, 0, stream>>>(v, vfpart);
  mix_kernel<<<NB * 4, 256, 0, stream>>>(vfpart, wre, wim, lvbuf);
  inv_dft_kernel<<<NROWS, TPB, 0, stream>>>(lvbuf, out);
}

// Round 2
// 45.830 us; speedup vs baseline: 1.2277x; 1.2277x over previous
//
#include <hip/hip_runtime.h>
#include <math.h>

#define NN 8192
#define NMODES 16
#define NB 32
#define NCH 64
#define NROWS (NB * NCH)       // 2048
#define TPB 256
#define JIT 8                  // 8192 / (256 threads * 4 floats)

#define K8 0.70710678118654752440f   // cos/sin(2*pi/8)

// fine-rotation constants e^{i 2*pi*k*c/8192}, k=0..15, c=0..3 (tiny angles,
// constexpr Taylor — exact to ~1e-16 rel at max angle 0.0345 rad)
struct KCTab { float c[16][4]; float s[16][4]; };
constexpr KCTab make_kc() {
  KCTab r{};
  for (int k = 0; k < 16; ++k)
    for (int c = 0; c < 4; ++c) {
      double th = 6.283185307179586476925287 * (double)(k * c) / 8192.0;
      double x2 = th * th;
      r.c[k][c] = (float)(1.0 - x2 / 2.0 + x2 * x2 / 24.0 - x2 * x2 * x2 / 720.0);
      r.s[k][c] = (float)(th - th * x2 / 6.0 + th * x2 * x2 / 120.0 - th * x2 * x2 * x2 / 5040.0);
    }
  return r;
}
constexpr KCTab KCT = make_kc();

// acc += x * e^{-i 2*pi*m/8}  (m compile-time after unroll -> branches fold,
// m in {0,2,4,6} costs a single add/sub)
__device__ __forceinline__ void rotacc8(int m, float x, float& br, float& bi) {
  switch (m) {
    case 0: br += x; break;
    case 1: br = fmaf(x,  K8, br); bi = fmaf(x, -K8, bi); break;
    case 2: bi -= x; break;
    case 3: br = fmaf(x, -K8, br); bi = fmaf(x, -K8, bi); break;
    case 4: br -= x; break;
    case 5: br = fmaf(x, -K8, br); bi = fmaf(x,  K8, bi); break;
    case 6: bi += x; break;
    default: br = fmaf(x,  K8, br); bi = fmaf(x,  K8, bi); break;
  }
}

// acc += Re(D * e^{+i 2*pi*m/8}) = Dr*cos - Di*sin
__device__ __forceinline__ float synth8(int m, float dr, float di, float acc) {
  switch (m) {
    case 0: return acc + dr;
    case 1: return fmaf(K8, dr - di, acc);
    case 2: return acc - di;
    case 3: return fmaf(-K8, dr + di, acc);
    case 4: return acc - dr;
    case 5: return fmaf(K8, di - dr, acc);
    case 6: return acc + di;
    default: return fmaf(K8, dr + di, acc);
  }
}

// Stage A: partial forward DFT, one block per (b, cin) row.
// n = 4t + 1024j + c; float4 loads; coarse twiddle = 8th roots (constants),
// fine per-c and per-thread rotations applied once in the epilogue.
// Stores 4 per-wave partials per row, interleaved (re,im) pairs.
__global__ __launch_bounds__(TPB) void fwd_dft_kernel(
    const float* __restrict__ v, float* __restrict__ vfpart) {
  const int row = blockIdx.x;
  const int t = threadIdx.x;
  const float4* __restrict__ vr4 = (const float4*)(v + (size_t)row * NN);

  float br[4][NMODES], bi[4][NMODES];
#pragma unroll
  for (int c = 0; c < 4; ++c)
#pragma unroll
    for (int k = 0; k < NMODES; ++k) { br[c][k] = 0.f; bi[c][k] = 0.f; }

#pragma unroll
  for (int j = 0; j < JIT; ++j) {
    const float4 x = vr4[t + TPB * j];
#pragma unroll
    for (int k = 0; k < NMODES; ++k) {
      const int m = (k * j) & 7;
      rotacc8(m, x.x, br[0][k], bi[0][k]);
      rotacc8(m, x.y, br[1][k], bi[1][k]);
      rotacc8(m, x.z, br[2][k], bi[2][k]);
      rotacc8(m, x.w, br[3][k], bi[3][k]);
    }
  }

  // per-thread base rotation e^{-i 2*pi*4t*k/8192}: one double sincos
  double phi = (double)t * (6.283185307179586476925287 / 2048.0);
  double spd, cpd;
  sincos(phi, &spd, &cpd);
  const float c1 = (float)cpd, s1 = (float)spd;

  float pr[NMODES], pi[NMODES];
  float ck = 1.f, sk = 0.f;   // (cos k*phi, sin k*phi)
#pragma unroll
  for (int k = 0; k < NMODES; ++k) {
    // combine c-slots with fine rotation e^{-i 2*pi*k*c/8192}
    float ar = br[0][k], ai = bi[0][k];
#pragma unroll
    for (int c = 1; c < 4; ++c) {
      ar = fmaf(br[c][k], KCT.c[k][c], fmaf(bi[c][k],  KCT.s[k][c], ar));
      ai = fmaf(bi[c][k], KCT.c[k][c], fmaf(br[c][k], -KCT.s[k][c], ai));
    }
    // rotate by e^{-i k phi}
    pr[k] = ar * ck + ai * sk;
    pi[k] = ai * ck - ar * sk;
    const float cn = ck * c1 - sk * s1;
    const float sn = sk * c1 + ck * s1;
    ck = cn; sk = sn;
  }

  // wave butterfly reduce
#pragma unroll
  for (int k = 0; k < NMODES; ++k) {
#pragma unroll
    for (int off = 32; off > 0; off >>= 1) {
      pr[k] += __shfl_xor(pr[k], off);
      pi[k] += __shfl_xor(pi[k], off);
    }
  }

  const int lane = t & 63, wave = t >> 6;
  if (lane == 0) {
    float* dst = vfpart + ((size_t)row * 4 + wave) * 32;
#pragma unroll
    for (int k = 0; k < NMODES; ++k) {
      dst[2 * k]     = pr[k];
      dst[2 * k + 1] = pi[k];
    }
  }
}

// Stage B: fused {sum wave partials + channel mix} prologue, then inverse
// synthesis with float4 stores. One block per (b, cout) row.
__global__ __launch_bounds__(TPB) void mix_inv_kernel(
    const float* __restrict__ vfpart, const float* __restrict__ wre,
    const float* __restrict__ wim, float* __restrict__ out) {
  const int bid = blockIdx.x;
  const int b = bid >> 6, o = bid & 63;
  const int t = threadIdx.x;

  __shared__ float red[16][33];
  __shared__ float lvs[32];

  // ---- mix: lv[k] = sum_i W[k,o,i] * vf[b,i,k] (also sums 4 wave partials)
  {
    const int k = t & 15, g = t >> 4;
    float lr = 0.f, li = 0.f;
#pragma unroll
    for (int ii = 0; ii < 4; ++ii) {
      const int i = g * 4 + ii;
      const float2* p2 = (const float2*)(vfpart + ((size_t)(b * NCH + i) * 4) * 32);
      float vr = 0.f, vi = 0.f;
#pragma unroll
      for (int w = 0; w < 4; ++w) {
        const float2 z = p2[w * 16 + k];
        vr += z.x; vi += z.y;
      }
      const float wr = wre[((size_t)k * NCH + o) * NCH + i];
      const float wi = wim[((size_t)k * NCH + o) * NCH + i];
      lr = fmaf(wr, vr, fmaf(-wi, vi, lr));
      li = fmaf(wr, vi, fmaf( wi, vr, li));
    }
    red[g][k]      = lr;
    red[g][16 + k] = li;
  }
  __syncthreads();
  if (t < 32) {
    float s = 0.f;
#pragma unroll
    for (int g = 0; g < 16; ++g) s += red[g][t];
    const float gk = ((t & 15) == 0) ? (1.0f / (float)NN) : (2.0f / (float)NN);
    lvs[t] = s * gk;   // lvs[k]=re, lvs[16+k]=im, scaled A_k
  }
  __syncthreads();

  // ---- build D_c[k] = A_k * e^{+i k phi} * e^{+i 2*pi*k*c/8192}
  double phi = (double)t * (6.283185307179586476925287 / 2048.0);
  double spd, cpd;
  sincos(phi, &spd, &cpd);
  const float c1 = (float)cpd, s1 = (float)spd;

  float Dr[4][NMODES], Di[4][NMODES];
  {
    float ck = 1.f, sk = 0.f;
#pragma unroll
    for (int k = 0; k < NMODES; ++k) {
      const float Ar = lvs[k], Ai = lvs[16 + k];
      const float xr = Ar * ck - Ai * sk;   // A_k * e^{+i k phi}
      const float xi = Ai * ck + Ar * sk;
      Dr[0][k] = xr; Di[0][k] = xi;
#pragma unroll
      for (int c = 1; c < 4; ++c) {
        Dr[c][k] = fmaf(xr, KCT.c[k][c], -xi * KCT.s[k][c]);
        Di[c][k] = fmaf(xi, KCT.c[k][c],  xr * KCT.s[k][c]);
      }
      const float cn = ck * c1 - sk * s1;
      const float sn = sk * c1 + ck * s1;
      ck = cn; sk = sn;
    }
  }

  // ---- synthesis: out[4t + 1024j + c] = sum_k Re(D_c[k] e^{+i 2 pi k j/8})
  float4* __restrict__ out4 = (float4*)(out + (size_t)bid * NN);
#pragma unroll
  for (int j = 0; j < JIT; ++j) {
    float a0 = 0.f, a1 = 0.f, a2 = 0.f, a3 = 0.f;
#pragma unroll
    for (int k = 0; k < NMODES; ++k) {
      const int m = (k * j) & 7;
      a0 = synth8(m, Dr[0][k], Di[0][k], a0);
      a1 = synth8(m, Dr[1][k], Di[1][k], a1);
      a2 = synth8(m, Dr[2][k], Di[2][k], a2);
      a3 = synth8(m, Dr[3][k], Di[3][k], a3);
    }
    float4 r; r.x = a0; r.y = a1; r.z = a2; r.w = a3;
    out4[t + TPB * j] = r;
  }
}

extern "C" void kernel_launch(void* const* d_in, const int* in_sizes, int n_in,
                              void* d_out, int out_size, void* d_ws, size_t ws_size,
                              hipStream_t stream) {
  const float* v   = (const float*)d_in[0];   // [32, 64, 8192]
  const float* wre = (const float*)d_in[1];   // [16, 64, 64]
  const float* wim = (const float*)d_in[2];   // [16, 64, 64]
  float* out = (float*)d_out;                 // [32, 64, 8192]

  float* vfpart = (float*)d_ws;               // 2048 * 4 * 32 floats = 1 MB

  fwd_dft_kernel<<<NROWS, TPB, 0, stream>>>(v, vfpart);
  mix_inv_kernel<<<NROWS, TPB, 0, stream>>>(vfpart, wre, wim, out);
}

// Round 3
// 34.894 us; speedup vs baseline: 1.6125x; 1.3134x over previous
//
#include <hip/hip_runtime.h>
#include <math.h>

#define NN 8192
#define NMODES 16
#define NB 32
#define NCH 64
#define NROWS (NB * NCH)       // 2048
#define TPB 256
#define JIT 8                  // 8192 / (256 threads * 4 floats)

#define K8 0.70710678118654752440f   // cos/sin(2*pi/8)

// fine-rotation constants e^{i 2*pi*k*c/8192}, k=0..15, c=0..3 (tiny angles,
// constexpr Taylor — exact to ~1e-16 rel at max angle 0.0345 rad)
struct KCTab { float c[16][4]; float s[16][4]; };
constexpr KCTab make_kc() {
  KCTab r{};
  for (int k = 0; k < 16; ++k)
    for (int c = 0; c < 4; ++c) {
      double th = 6.283185307179586476925287 * (double)(k * c) / 8192.0;
      double x2 = th * th;
      r.c[k][c] = (float)(1.0 - x2 / 2.0 + x2 * x2 / 24.0 - x2 * x2 * x2 / 720.0);
      r.s[k][c] = (float)(th - th * x2 / 6.0 + th * x2 * x2 / 120.0 - th * x2 * x2 * x2 / 5040.0);
    }
  return r;
}
constexpr KCTab KCT = make_kc();

// acc += x * e^{-i 2*pi*m/8}  (m compile-time after unroll -> branches fold,
// m in {0,2,4,6} costs a single add/sub)
__device__ __forceinline__ void rotacc8(int m, float x, float& br, float& bi) {
  switch (m) {
    case 0: br += x; break;
    case 1: br = fmaf(x,  K8, br); bi = fmaf(x, -K8, bi); break;
    case 2: bi -= x; break;
    case 3: br = fmaf(x, -K8, br); bi = fmaf(x, -K8, bi); break;
    case 4: br -= x; break;
    case 5: br = fmaf(x, -K8, br); bi = fmaf(x,  K8, bi); break;
    case 6: bi += x; break;
    default: br = fmaf(x,  K8, br); bi = fmaf(x,  K8, bi); break;
  }
}

// acc += Re(D * e^{+i 2*pi*m/8}) = Dr*cos - Di*sin
__device__ __forceinline__ float synth8(int m, float dr, float di, float acc) {
  switch (m) {
    case 0: return acc + dr;
    case 1: return fmaf(K8, dr - di, acc);
    case 2: return acc - di;
    case 3: return fmaf(-K8, dr + di, acc);
    case 4: return acc - dr;
    case 5: return fmaf(K8, di - dr, acc);
    case 6: return acc + di;
    default: return fmaf(K8, dr + di, acc);
  }
}

// Stage A: partial forward DFT, one block per (b, cin) row.
// n = 4t + 1024j + c. Coarse twiddle e^{-2pi i k j/8}: modes k and k+8 are
// IDENTICAL (kj == (k+8)j mod 8), so only 8 mode-class accumulators are kept;
// the 16-mode expansion happens in the epilogue where fine rotations differ.
// Reduction: distributed halving exchange (each lane keeps the slot-half
// matching its lane bit) -> lane L ends owning slot L&31; coalesced store.
__global__ __launch_bounds__(TPB) void fwd_dft_kernel(
    const float* __restrict__ v, float* __restrict__ vfpart) {
  const int row = blockIdx.x;
  const int t = threadIdx.x;
  const float4* __restrict__ vr4 = (const float4*)(v + (size_t)row * NN);

  float br[4][8], bi[4][8];
#pragma unroll
  for (int c = 0; c < 4; ++c)
#pragma unroll
    for (int m = 0; m < 8; ++m) { br[c][m] = 0.f; bi[c][m] = 0.f; }

#pragma unroll
  for (int j = 0; j < JIT; ++j) {
    const float4 x = vr4[t + TPB * j];
#pragma unroll
    for (int m = 0; m < 8; ++m) {
      const int e = (m * j) & 7;
      rotacc8(e, x.x, br[0][m], bi[0][m]);
      rotacc8(e, x.y, br[1][m], bi[1][m]);
      rotacc8(e, x.z, br[2][m], bi[2][m]);
      rotacc8(e, x.w, br[3][m], bi[3][m]);
    }
  }

  // per-thread base rotation e^{-i 2*pi*4t*k/8192}: one double sincos
  double phi = (double)t * (6.283185307179586476925287 / 2048.0);
  double spd, cpd;
  sincos(phi, &spd, &cpd);
  const float c1 = (float)cpd, s1 = (float)spd;

  float pr[NMODES], pi[NMODES];
  float ck = 1.f, sk = 0.f;   // (cos k*phi, sin k*phi)
#pragma unroll
  for (int k = 0; k < NMODES; ++k) {
    const int m = k & 7;
    // combine c-slots with fine rotation e^{-i 2*pi*k*c/8192}
    float ar = br[0][m], ai = bi[0][m];
#pragma unroll
    for (int c = 1; c < 4; ++c) {
      ar = fmaf(br[c][m], KCT.c[k][c], fmaf(bi[c][m],  KCT.s[k][c], ar));
      ai = fmaf(bi[c][m], KCT.c[k][c], fmaf(br[c][m], -KCT.s[k][c], ai));
    }
    // rotate by e^{-i k phi}
    pr[k] = ar * ck + ai * sk;
    pi[k] = ai * ck - ar * sk;
    const float cn = ck * c1 - sk * s1;
    const float sn = sk * c1 + ck * s1;
    ck = cn; sk = sn;
  }

  // distributed reduce: slot s (0..31) = [pr[0..15], pi[0..15]];
  // at xor-level d, keep slots with (s&d)==(lane&d) -> final slot = lane&31
  const int lane = t & 63, wave = t >> 6;

  float u16[16];
  {
    const bool hi = (lane & 16) != 0;
#pragma unroll
    for (int i = 0; i < 16; ++i) {
      const float send = hi ? pr[i] : pi[i];
      const float recv = __shfl_xor(send, 16);
      u16[i] = (hi ? pi[i] : pr[i]) + recv;
    }
  }
  float u8[8];
  {
    const bool hi = (lane & 8) != 0;
#pragma unroll
    for (int i = 0; i < 8; ++i) {
      const float send = hi ? u16[i] : u16[i + 8];
      const float recv = __shfl_xor(send, 8);
      u8[i] = (hi ? u16[i + 8] : u16[i]) + recv;
    }
  }
  float u4[4];
  {
    const bool hi = (lane & 4) != 0;
#pragma unroll
    for (int i = 0; i < 4; ++i) {
      const float send = hi ? u8[i] : u8[i + 4];
      const float recv = __shfl_xor(send, 4);
      u4[i] = (hi ? u8[i + 4] : u8[i]) + recv;
    }
  }
  float u2[2];
  {
    const bool hi = (lane & 2) != 0;
#pragma unroll
    for (int i = 0; i < 2; ++i) {
      const float send = hi ? u4[i] : u4[i + 2];
      const float recv = __shfl_xor(send, 2);
      u2[i] = (hi ? u4[i + 2] : u4[i]) + recv;
    }
  }
  float u1;
  {
    const bool hi = (lane & 1) != 0;
    const float send = hi ? u2[0] : u2[1];
    const float recv = __shfl_xor(send, 1);
    u1 = (hi ? u2[1] : u2[0]) + recv;
  }
  const float total = u1 + __shfl_xor(u1, 32);

  if (lane < 32) {
    // planar layout: part[w*32 + s], s<16: Re(mode s), s>=16: Im(mode s-16)
    vfpart[((size_t)row * 4 + wave) * 32 + lane] = total;
  }
}

// Stage B: fused {sum wave partials + channel mix} prologue, then inverse
// synthesis. Modes k and k+8 share the coarse factor e^{+2pi i k j/8}, so
// after the per-thread rotation they are folded (E[m] = D[m] + D[m+8]) and
// the synthesis inner loop runs over 8 mode-classes only.
__global__ __launch_bounds__(TPB) void mix_inv_kernel(
    const float* __restrict__ vfpart, const float* __restrict__ wre,
    const float* __restrict__ wim, float* __restrict__ out) {
  const int bid = blockIdx.x;
  const int b = bid >> 6, o = bid & 63;
  const int t = threadIdx.x;

  __shared__ float red[16][33];
  __shared__ float lvs[32];

  // ---- mix: lv[k] = sum_i W[k,o,i] * vf[b,i,k] (also sums 4 wave partials)
  {
    const int k = t & 15, g = t >> 4;
    float lr = 0.f, li = 0.f;
#pragma unroll
    for (int ii = 0; ii < 4; ++ii) {
      const int i = g * 4 + ii;
      const float* __restrict__ p = vfpart + (size_t)(b * NCH + i) * 128;
      float vr = 0.f, vi = 0.f;
#pragma unroll
      for (int w = 0; w < 4; ++w) {
        vr += p[w * 32 + k];
        vi += p[w * 32 + 16 + k];
      }
      const float wr = wre[((size_t)k * NCH + o) * NCH + i];
      const float wi = wim[((size_t)k * NCH + o) * NCH + i];
      lr = fmaf(wr, vr, fmaf(-wi, vi, lr));
      li = fmaf(wr, vi, fmaf( wi, vr, li));
    }
    red[g][k]      = lr;
    red[g][16 + k] = li;
  }
  __syncthreads();
  if (t < 32) {
    float s = 0.f;
#pragma unroll
    for (int g = 0; g < 16; ++g) s += red[g][t];
    const float gk = ((t & 15) == 0) ? (1.0f / (float)NN) : (2.0f / (float)NN);
    lvs[t] = s * gk;   // lvs[k]=re, lvs[16+k]=im, scaled A_k
  }
  __syncthreads();

  // ---- build D_c[k] = A_k * e^{+i k phi} * e^{+i 2*pi*k*c/8192}, then fold
  double phi = (double)t * (6.283185307179586476925287 / 2048.0);
  double spd, cpd;
  sincos(phi, &spd, &cpd);
  const float c1 = (float)cpd, s1 = (float)spd;

  float Er[4][8], Ei[4][8];
  {
    float Dr[4][NMODES], Di[4][NMODES];
    float ck = 1.f, sk = 0.f;
#pragma unroll
    for (int k = 0; k < NMODES; ++k) {
      const float Ar = lvs[k], Ai = lvs[16 + k];
      const float xr = Ar * ck - Ai * sk;   // A_k * e^{+i k phi}
      const float xi = Ai * ck + Ar * sk;
      Dr[0][k] = xr; Di[0][k] = xi;
#pragma unroll
      for (int c = 1; c < 4; ++c) {
        Dr[c][k] = fmaf(xr, KCT.c[k][c], -xi * KCT.s[k][c]);
        Di[c][k] = fmaf(xi, KCT.c[k][c],  xr * KCT.s[k][c]);
      }
      const float cn = ck * c1 - sk * s1;
      const float sn = sk * c1 + ck * s1;
      ck = cn; sk = sn;
    }
    // fold k and k+8 (identical coarse synthesis factor)
#pragma unroll
    for (int c = 0; c < 4; ++c)
#pragma unroll
      for (int m = 0; m < 8; ++m) {
        Er[c][m] = Dr[c][m] + Dr[c][m + 8];
        Ei[c][m] = Di[c][m] + Di[c][m + 8];
      }
  }

  // ---- synthesis: out[4t + 1024j + c] = sum_m Re(E_c[m] e^{+i 2 pi m j/8})
  float4* __restrict__ out4 = (float4*)(out + (size_t)bid * NN);
#pragma unroll
  for (int j = 0; j < JIT; ++j) {
    float a0 = 0.f, a1 = 0.f, a2 = 0.f, a3 = 0.f;
#pragma unroll
    for (int m = 0; m < 8; ++m) {
      const int e = (m * j) & 7;
      a0 = synth8(e, Er[0][m], Ei[0][m], a0);
      a1 = synth8(e, Er[1][m], Ei[1][m], a1);
      a2 = synth8(e, Er[2][m], Ei[2][m], a2);
      a3 = synth8(e, Er[3][m], Ei[3][m], a3);
    }
    float4 r; r.x = a0; r.y = a1; r.z = a2; r.w = a3;
    out4[t + TPB * j] = r;
  }
}

extern "C" void kernel_launch(void* const* d_in, const int* in_sizes, int n_in,
                              void* d_out, int out_size, void* d_ws, size_t ws_size,
                              hipStream_t stream) {
  const float* v   = (const float*)d_in[0];   // [32, 64, 8192]
  const float* wre = (const float*)d_in[1];   // [16, 64, 64]
  const float* wim = (const float*)d_in[2];   // [16, 64, 64]
  float* out = (float*)d_out;                 // [32, 64, 8192]

  float* vfpart = (float*)d_ws;               // 2048 * 4 * 32 floats = 1 MB

  fwd_dft_kernel<<<NROWS, TPB, 0, stream>>>(v, vfpart);
  mix_inv_kernel<<<NROWS, TPB, 0, stream>>>(vfpart, wre, wim, out);
}